// Round 2
// baseline (620.002 us; speedup 1.0000x reference)
//
#include <hip/hip_runtime.h>
#include <hip/hip_bf16.h>
#include <cstdint>

#define NB 4
#define TT 2048
#define DM 1024
#define NH 16
#define HD 64

typedef __attribute__((ext_vector_type(8))) short bf16x8;
typedef __attribute__((ext_vector_type(4))) float f32x4;
typedef __attribute__((ext_vector_type(4))) float float4v;

static __device__ __forceinline__ unsigned short f2bf(float x) {
    unsigned int u = __float_as_uint(x);
    unsigned int r = (u + 0x7fffu + ((u >> 16) & 1u)) >> 16;
    return (unsigned short)r;
}

// ---- W[k][n] f32 -> Wt[n][k] bf16 (transpose + convert) ----
__global__ __launch_bounds__(256) void k_transpose_w(const float* __restrict__ W,
                                                     unsigned short* __restrict__ Wt) {
    __shared__ unsigned short tile[32][33];
    int tx = threadIdx.x, ty = threadIdx.y;
    int kb = blockIdx.x * 32, nb = blockIdx.y * 32;
#pragma unroll
    for (int i = 0; i < 4; ++i)
        tile[ty + i * 8][tx] = f2bf(W[(size_t)(kb + ty + i * 8) * DM + nb + tx]);
    __syncthreads();
#pragma unroll
    for (int i = 0; i < 4; ++i)
        Wt[(size_t)(nb + ty + i * 8) * DM + kb + tx] = tile[tx][ty + i * 8];
}

// ---- V[bh][t][d] bf16 -> Vt[bh][d][t] bf16 ----
__global__ __launch_bounds__(256) void k_transpose_v(const unsigned short* __restrict__ V,
                                                     unsigned short* __restrict__ Vt) {
    __shared__ unsigned short tile[32][34];
    int tx = threadIdx.x, ty = threadIdx.y;
    int bh = blockIdx.z;
    int t0 = blockIdx.x * 32, d0 = blockIdx.y * 32;
    const unsigned short* src = V + (size_t)bh * TT * HD;
    unsigned short* dst = Vt + (size_t)bh * HD * TT;
#pragma unroll
    for (int i = 0; i < 4; ++i)
        tile[ty + i * 8][tx] = src[(size_t)(t0 + ty + i * 8) * HD + d0 + tx];
    __syncthreads();
#pragma unroll
    for (int i = 0; i < 4; ++i)
        dst[(size_t)(d0 + ty + i * 8) * TT + t0 + tx] = tile[tx][ty + i * 8];
}

// ---- GEMM: C[M=8192][1024] = A[M][1024] @ W[1024][1024] (+bias)*scale ----
// Bt is W transposed: Bt[n][k].  OUT_MODE 0: scatter bf16 to [b,h,t,d]; 1: f32 row-major.
template <int OUT_MODE, bool A_BF16>
__global__ __launch_bounds__(256) void k_gemm(const void* __restrict__ Av,
                                              const unsigned short* __restrict__ Bt,
                                              const float* __restrict__ bias,
                                              void* __restrict__ Cv, float scale) {
    __shared__ __align__(16) unsigned short As[128][56];
    __shared__ __align__(16) unsigned short Bs[128][56];
    const int tid = threadIdx.x;
    const int lane = tid & 63, wid = tid >> 6;
    const int lg = lane >> 4, lc = lane & 15;
    const int wm = wid >> 1, wn = wid & 1;
    const int m0 = blockIdx.x * 128, n0 = blockIdx.y * 128;

    f32x4 acc[4][4];
#pragma unroll
    for (int mi = 0; mi < 4; ++mi)
#pragma unroll
        for (int ni = 0; ni < 4; ++ni)
            acc[mi][ni] = (f32x4){0.f, 0.f, 0.f, 0.f};

    for (int k0 = 0; k0 < DM; k0 += 32) {
        __syncthreads();
        if (!A_BF16) {
            const float* A = (const float*)Av;
#pragma unroll
            for (int p = 0; p < 4; ++p) {
                int r = p * 32 + (tid >> 3);
                int cs = (tid & 7) * 4;
                float4v v = *(const float4v*)(A + (size_t)(m0 + r) * DM + k0 + cs);
                As[r][cs + 0] = f2bf(v[0]);
                As[r][cs + 1] = f2bf(v[1]);
                As[r][cs + 2] = f2bf(v[2]);
                As[r][cs + 3] = f2bf(v[3]);
            }
        } else {
            const unsigned short* A = (const unsigned short*)Av;
#pragma unroll
            for (int p = 0; p < 2; ++p) {
                int r = p * 64 + (tid >> 2), seg = tid & 3;
                bf16x8 v = *(const bf16x8*)(A + (size_t)(m0 + r) * DM + k0 + seg * 8);
                *(bf16x8*)(&As[r][seg * 8]) = v;
            }
        }
#pragma unroll
        for (int p = 0; p < 2; ++p) {
            int r = p * 64 + (tid >> 2), seg = tid & 3;
            bf16x8 v = *(const bf16x8*)(Bt + (size_t)(n0 + r) * DM + k0 + seg * 8);
            *(bf16x8*)(&Bs[r][seg * 8]) = v;
        }
        __syncthreads();

        bf16x8 af[4], bfr[4];
#pragma unroll
        for (int mi = 0; mi < 4; ++mi)
            af[mi] = *(const bf16x8*)(&As[wm * 64 + mi * 16 + lc][lg * 8]);
#pragma unroll
        for (int ni = 0; ni < 4; ++ni)
            bfr[ni] = *(const bf16x8*)(&Bs[wn * 64 + ni * 16 + lc][lg * 8]);
#pragma unroll
        for (int mi = 0; mi < 4; ++mi)
#pragma unroll
            for (int ni = 0; ni < 4; ++ni)
                acc[mi][ni] = __builtin_amdgcn_mfma_f32_16x16x32_bf16(af[mi], bfr[ni],
                                                                      acc[mi][ni], 0, 0, 0);
    }

#pragma unroll
    for (int mi = 0; mi < 4; ++mi)
#pragma unroll
        for (int ni = 0; ni < 4; ++ni)
#pragma unroll
            for (int r = 0; r < 4; ++r) {
                int m = m0 + wm * 64 + mi * 16 + lg * 4 + r;
                int n = n0 + wn * 64 + ni * 16 + lc;
                float val = (acc[mi][ni][r] + bias[n]) * scale;
                if (OUT_MODE == 0) {
                    int b = m >> 11, t = m & (TT - 1), h = n >> 6, d = n & 63;
                    ((unsigned short*)Cv)[(((size_t)b * NH + h) * TT + t) * HD + d] = f2bf(val);
                } else {
                    ((float*)Cv)[(size_t)m * DM + n] = val;
                }
            }
}

// ---- flash attention (barrier-free kv loop) ----
// Q,K bf16 [bh][t][64]; Vt bf16 [bh][d][t]; out bf16 [b*T+t][h*64+d]
// Q is pre-scaled by log2(e)/sqrt(D); softmax runs in exp2 domain.
__global__ __launch_bounds__(256) void k_attn(const unsigned short* __restrict__ Qg,
                                              const unsigned short* __restrict__ Kg,
                                              const unsigned short* __restrict__ Vtg,
                                              const int* __restrict__ pm,
                                              unsigned short* __restrict__ Og) {
    const int bh = blockIdx.y;
    const int b = bh >> 4, h = bh & 15;
    const int qt = gridDim.x - 1 - blockIdx.x;  // heavy blocks first
    const int qbase = qt * 64;
    const int tid = threadIdx.x;
    const int wid = tid >> 6, lane = tid & 63;
    const int lg = lane >> 4, lc = lane & 15;
    const int qw = qbase + wid * 16;

    const unsigned short* Qh = Qg + (size_t)bh * TT * HD;
    const unsigned short* Kh = Kg + (size_t)bh * TT * HD;
    const unsigned short* Vth = Vtg + (size_t)bh * HD * TT;
    const int* pmb = pm + b * TT;

    // hoist Q fragments (16 q-rows x 64 d per wave)
    const int qrow = qw + lc;
    bf16x8 qf0 = *(const bf16x8*)(Qh + (size_t)qrow * HD + lg * 8);
    bf16x8 qf1 = *(const bf16x8*)(Qh + (size_t)qrow * HD + 32 + lg * 8);

    f32x4 accd[4];
#pragma unroll
    for (int dc = 0; dc < 4; ++dc) accd[dc] = (f32x4){0.f, 0.f, 0.f, 0.f};
    float mrow[4] = {-INFINITY, -INFINITY, -INFINITY, -INFINITY};
    float lrow[4] = {0.f, 0.f, 0.f, 0.f};

    __shared__ __align__(16) unsigned short Pl[4][16][72];  // per-wave P[q][k], 64 keys + pad

    for (int kv0 = 0; kv0 < qbase + 64; kv0 += 64) {
        const int ktmax = min(3, (qw + 15 - kv0) >> 4);  // wave-uniform causal tile cap
        f32x4 s[4];
        int pmv[4] = {1, 1, 1, 1};
#pragma unroll
        for (int kt = 0; kt < 4; ++kt) {
            s[kt] = (f32x4){0.f, 0.f, 0.f, 0.f};
            if (kt <= ktmax) {
                const int key = kv0 + kt * 16 + lc;
                pmv[kt] = pmb[key];
                const unsigned short* kp = Kh + (size_t)key * HD;
                bf16x8 kf0 = *(const bf16x8*)(kp + lg * 8);
                bf16x8 kf1 = *(const bf16x8*)(kp + 32 + lg * 8);
                s[kt] = __builtin_amdgcn_mfma_f32_16x16x32_bf16(qf0, kf0, s[kt], 0, 0, 0);
                s[kt] = __builtin_amdgcn_mfma_f32_16x16x32_bf16(qf1, kf1, s[kt], 0, 0, 0);
            }
        }

#pragma unroll
        for (int r = 0; r < 4; ++r) {
            const int qg = qw + lg * 4 + r;
            float v[4];
#pragma unroll
            for (int kt = 0; kt < 4; ++kt) {
                const int key = kv0 + kt * 16 + lc;
                v[kt] = (key > qg || pmv[kt] == 0) ? -INFINITY : s[kt][r];
            }
            float tmax = fmaxf(fmaxf(v[0], v[1]), fmaxf(v[2], v[3]));
            tmax = fmaxf(tmax, __shfl_xor(tmax, 1));
            tmax = fmaxf(tmax, __shfl_xor(tmax, 2));
            tmax = fmaxf(tmax, __shfl_xor(tmax, 4));
            tmax = fmaxf(tmax, __shfl_xor(tmax, 8));
            const float mnew = fmaxf(mrow[r], tmax);
            const float esc = __builtin_amdgcn_exp2f(mrow[r] - mnew);
            float e[4];
            float ps = 0.f;
#pragma unroll
            for (int kt = 0; kt < 4; ++kt) {
                e[kt] = __builtin_amdgcn_exp2f(v[kt] - mnew);
                ps += e[kt];
            }
            ps += __shfl_xor(ps, 1);
            ps += __shfl_xor(ps, 2);
            ps += __shfl_xor(ps, 4);
            ps += __shfl_xor(ps, 8);
            lrow[r] = lrow[r] * esc + ps;
            mrow[r] = mnew;
#pragma unroll
            for (int dc = 0; dc < 4; ++dc) accd[dc][r] *= esc;
#pragma unroll
            for (int kt = 0; kt < 4; ++kt)
                Pl[wid][lg * 4 + r][kt * 16 + lc] = f2bf(e[kt]);
        }

        // PV: A = P[16 q][64 k] from per-wave LDS, B = V^T direct from global (L2)
        bf16x8 pa0 = *(const bf16x8*)(&Pl[wid][lc][lg * 8]);
        bf16x8 pa1 = *(const bf16x8*)(&Pl[wid][lc][32 + lg * 8]);
#pragma unroll
        for (int dc = 0; dc < 4; ++dc) {
            const unsigned short* vp = Vth + (size_t)(dc * 16 + lc) * TT + kv0;
            bf16x8 vb0 = *(const bf16x8*)(vp + lg * 8);
            bf16x8 vb1 = *(const bf16x8*)(vp + 32 + lg * 8);
            accd[dc] = __builtin_amdgcn_mfma_f32_16x16x32_bf16(pa0, vb0, accd[dc], 0, 0, 0);
            accd[dc] = __builtin_amdgcn_mfma_f32_16x16x32_bf16(pa1, vb1, accd[dc], 0, 0, 0);
        }
    }

    // epilogue: normalize, write [b*T+t][h*64+d] bf16
#pragma unroll
    for (int r = 0; r < 4; ++r) {
        float inv = 1.0f / lrow[r];
        int qg = qw + lg * 4 + r;
#pragma unroll
        for (int dc = 0; dc < 4; ++dc) {
            float val = accd[dc][r] * inv;
            Og[((size_t)b * TT + qg) * DM + h * HD + dc * 16 + lc] = f2bf(val);
        }
    }
}

extern "C" void kernel_launch(void* const* d_in, const int* in_sizes, int n_in,
                              void* d_out, int out_size, void* d_ws, size_t ws_size,
                              hipStream_t stream) {
    const float* xq = (const float*)d_in[0];
    const float* xk = (const float*)d_in[1];
    const float* xv = (const float*)d_in[2];
    const int* pmask = (const int*)d_in[3];
    const float* Wq = (const float*)d_in[4];
    const float* bq = (const float*)d_in[5];
    const float* Wk = (const float*)d_in[6];
    const float* bk = (const float*)d_in[7];
    const float* Wv = (const float*)d_in[8];
    const float* bv = (const float*)d_in[9];
    const float* Wo = (const float*)d_in[10];
    const float* bo = (const float*)d_in[11];

    char* ws = (char*)d_ws;
    const size_t WT = (size_t)DM * DM * 2;             // 2 MB per transposed weight
    const size_t QKV = (size_t)NB * NH * TT * HD * 2;  // 16 MB each
    unsigned short* WqT = (unsigned short*)(ws + 0 * WT);
    unsigned short* WkT = (unsigned short*)(ws + 1 * WT);
    unsigned short* WvT = (unsigned short*)(ws + 2 * WT);
    unsigned short* WoT = (unsigned short*)(ws + 3 * WT);
    unsigned short* Qb = (unsigned short*)(ws + 4 * WT);
    unsigned short* Kb = (unsigned short*)(ws + 4 * WT + QKV);
    unsigned short* Vb = (unsigned short*)(ws + 4 * WT + 2 * QKV);
    unsigned short* Vt = (unsigned short*)(ws + 4 * WT + 3 * QKV);
    unsigned short* Ob = Vb;  // Vb is dead after k_transpose_v; reuse for attn output

    dim3 tb(32, 8);
    k_transpose_w<<<dim3(32, 32), tb, 0, stream>>>(Wq, WqT);
    k_transpose_w<<<dim3(32, 32), tb, 0, stream>>>(Wk, WkT);
    k_transpose_w<<<dim3(32, 32), tb, 0, stream>>>(Wv, WvT);
    k_transpose_w<<<dim3(32, 32), tb, 0, stream>>>(Wo, WoT);

    const float qscale = 0.125f * 1.44269504088896340736f;  // 1/sqrt(64) * log2(e)
    dim3 gg(64, 8);  // M/128, N/128
    k_gemm<0, false><<<gg, 256, 0, stream>>>(xq, WqT, bq, Qb, qscale);
    k_gemm<0, false><<<gg, 256, 0, stream>>>(xk, WkT, bk, Kb, 1.0f);
    k_gemm<0, false><<<gg, 256, 0, stream>>>(xv, WvT, bv, Vb, 1.0f);

    k_transpose_v<<<dim3(TT / 32, HD / 32, NB * NH), tb, 0, stream>>>(Vb, Vt);

    k_attn<<<dim3(TT / 64, NB * NH), 256, 0, stream>>>(Qb, Kb, Vt, pmask, Ob);

    k_gemm<1, true><<<gg, 256, 0, stream>>>(Ob, WoT, bo, d_out, 1.0f);
}

// Round 3
// 505.022 us; speedup vs baseline: 1.2277x; 1.2277x over previous
//
#include <hip/hip_runtime.h>
#include <hip/hip_bf16.h>
#include <cstdint>

#define NB 4
#define TT 2048
#define DM 1024
#define NH 16
#define HD 64
#define QBLK 128
#define KVB 64

typedef __attribute__((ext_vector_type(8))) short bf16x8;
typedef __attribute__((ext_vector_type(4))) float f32x4;
typedef __attribute__((ext_vector_type(4))) float float4v;

static __device__ __forceinline__ unsigned short f2bf(float x) {
    unsigned int u = __float_as_uint(x);
    unsigned int r = (u + 0x7fffu + ((u >> 16) & 1u)) >> 16;
    return (unsigned short)r;
}

#define GLOAD16(gp, lp) __builtin_amdgcn_global_load_lds(                 \
    (const __attribute__((address_space(1))) void*)(gp),                  \
    (__attribute__((address_space(3))) void*)(lp), 16, 0, 0)
#define BAR() asm volatile("s_barrier" ::: "memory")
#define WAITV4() asm volatile("s_waitcnt vmcnt(4)" ::: "memory")
#define WAITV0() asm volatile("s_waitcnt vmcnt(0)" ::: "memory")

// ---- W[k][n] f32 -> Wt[n][k] bf16 (transpose + convert) ----
__global__ __launch_bounds__(256) void k_transpose_w(const float* __restrict__ W,
                                                     unsigned short* __restrict__ Wt) {
    __shared__ unsigned short tile[32][33];
    int tx = threadIdx.x, ty = threadIdx.y;
    int kb = blockIdx.x * 32, nb = blockIdx.y * 32;
#pragma unroll
    for (int i = 0; i < 4; ++i)
        tile[ty + i * 8][tx] = f2bf(W[(size_t)(kb + ty + i * 8) * DM + nb + tx]);
    __syncthreads();
#pragma unroll
    for (int i = 0; i < 4; ++i)
        Wt[(size_t)(nb + ty + i * 8) * DM + kb + tx] = tile[tx][ty + i * 8];
}

// ---- V[bh][t][d] bf16 -> Vt[bh][d][t] bf16 ----
__global__ __launch_bounds__(256) void k_transpose_v(const unsigned short* __restrict__ V,
                                                     unsigned short* __restrict__ Vt) {
    __shared__ unsigned short tile[32][34];
    int tx = threadIdx.x, ty = threadIdx.y;
    int bh = blockIdx.z;
    int t0 = blockIdx.x * 32, d0 = blockIdx.y * 32;
    const unsigned short* src = V + (size_t)bh * TT * HD;
    unsigned short* dst = Vt + (size_t)bh * HD * TT;
#pragma unroll
    for (int i = 0; i < 4; ++i)
        tile[ty + i * 8][tx] = src[(size_t)(t0 + ty + i * 8) * HD + d0 + tx];
    __syncthreads();
#pragma unroll
    for (int i = 0; i < 4; ++i)
        dst[(size_t)(d0 + ty + i * 8) * TT + t0 + tx] = tile[tx][ty + i * 8];
}

// ---- GEMM: C[M=8192][1024] = A[M][1024] @ W[1024][1024] (+bias)*scale ----
template <int OUT_MODE, bool A_BF16>
__global__ __launch_bounds__(256) void k_gemm(const void* __restrict__ Av,
                                              const unsigned short* __restrict__ Bt,
                                              const float* __restrict__ bias,
                                              void* __restrict__ Cv, float scale) {
    __shared__ __align__(16) unsigned short As[128][56];
    __shared__ __align__(16) unsigned short Bs[128][56];
    const int tid = threadIdx.x;
    const int lane = tid & 63, wid = tid >> 6;
    const int lg = lane >> 4, lc = lane & 15;
    const int wm = wid >> 1, wn = wid & 1;
    const int m0 = blockIdx.x * 128, n0 = blockIdx.y * 128;

    f32x4 acc[4][4];
#pragma unroll
    for (int mi = 0; mi < 4; ++mi)
#pragma unroll
        for (int ni = 0; ni < 4; ++ni)
            acc[mi][ni] = (f32x4){0.f, 0.f, 0.f, 0.f};

    for (int k0 = 0; k0 < DM; k0 += 32) {
        __syncthreads();
        if (!A_BF16) {
            const float* A = (const float*)Av;
#pragma unroll
            for (int p = 0; p < 4; ++p) {
                int r = p * 32 + (tid >> 3);
                int cs = (tid & 7) * 4;
                float4v v = *(const float4v*)(A + (size_t)(m0 + r) * DM + k0 + cs);
                As[r][cs + 0] = f2bf(v[0]);
                As[r][cs + 1] = f2bf(v[1]);
                As[r][cs + 2] = f2bf(v[2]);
                As[r][cs + 3] = f2bf(v[3]);
            }
        } else {
            const unsigned short* A = (const unsigned short*)Av;
#pragma unroll
            for (int p = 0; p < 2; ++p) {
                int r = p * 64 + (tid >> 2), seg = tid & 3;
                bf16x8 v = *(const bf16x8*)(A + (size_t)(m0 + r) * DM + k0 + seg * 8);
                *(bf16x8*)(&As[r][seg * 8]) = v;
            }
        }
#pragma unroll
        for (int p = 0; p < 2; ++p) {
            int r = p * 64 + (tid >> 2), seg = tid & 3;
            bf16x8 v = *(const bf16x8*)(Bt + (size_t)(n0 + r) * DM + k0 + seg * 8);
            *(bf16x8*)(&Bs[r][seg * 8]) = v;
        }
        __syncthreads();

        bf16x8 af[4], bfr[4];
#pragma unroll
        for (int mi = 0; mi < 4; ++mi)
            af[mi] = *(const bf16x8*)(&As[wm * 64 + mi * 16 + lc][lg * 8]);
#pragma unroll
        for (int ni = 0; ni < 4; ++ni)
            bfr[ni] = *(const bf16x8*)(&Bs[wn * 64 + ni * 16 + lc][lg * 8]);
#pragma unroll
        for (int mi = 0; mi < 4; ++mi)
#pragma unroll
            for (int ni = 0; ni < 4; ++ni)
                acc[mi][ni] = __builtin_amdgcn_mfma_f32_16x16x32_bf16(af[mi], bfr[ni],
                                                                      acc[mi][ni], 0, 0, 0);
    }

#pragma unroll
    for (int mi = 0; mi < 4; ++mi)
#pragma unroll
        for (int ni = 0; ni < 4; ++ni)
#pragma unroll
            for (int r = 0; r < 4; ++r) {
                int m = m0 + wm * 64 + mi * 16 + lg * 4 + r;
                int n = n0 + wn * 64 + ni * 16 + lc;
                float val = (acc[mi][ni][r] + bias[n]) * scale;
                if (OUT_MODE == 0) {
                    int b = m >> 11, t = m & (TT - 1), h = n >> 6, d = n & 63;
                    ((unsigned short*)Cv)[(((size_t)b * NH + h) * TT + t) * HD + d] = f2bf(val);
                } else {
                    ((float*)Cv)[(size_t)m * DM + n] = val;
                }
            }
}

// ---- flash attention, shared-LDS staged K/V with counted-vmcnt pipeline ----
// Q,K bf16 [bh][t][64]; Vt bf16 [bh][d][t]; out bf16 [b*T+t][h*64+d]
// LDS K/V tiles are XOR-swizzled: LDS byte (row*128+c) holds global col byte
// c ^ ((row&7)<<4). Staged linearly by global_load_lds with pre-swizzled
// global source (rule 21); reads apply the same XOR.
__global__ __launch_bounds__(256) void k_attn(const unsigned short* __restrict__ Qg,
                                              const unsigned short* __restrict__ Kg,
                                              const unsigned short* __restrict__ Vtg,
                                              const int* __restrict__ pm,
                                              unsigned short* __restrict__ Og) {
    __shared__ __align__(16) unsigned short Kl[2][KVB * HD];  // 8 KB each buf
    __shared__ __align__(16) unsigned short Vl[2][KVB * HD];  // V^T tile [d][k]
    __shared__ __align__(16) unsigned short Pl[4][32][72];    // per-wave P
    __shared__ char pml[TT];

    const int bh = blockIdx.y;
    const int b = bh >> 4, h = bh & 15;
    const int qt = gridDim.x - 1 - blockIdx.x;  // heavy blocks first
    const int qbase = qt * QBLK;
    const int tid = threadIdx.x;
    const int wid = tid >> 6, lane = tid & 63;
    const int lg = lane >> 4, lc = lane & 15;
    const int qw = qbase + wid * 32;

    const unsigned short* Qh = Qg + (size_t)bh * TT * HD;
    const char* Khb = (const char*)(Kg + (size_t)bh * TT * HD);
    const char* Vthb = (const char*)(Vtg + (size_t)bh * HD * TT);
    const int* pmb = pm + b * TT;

    // stage padding mask once (bytes)
    for (int i = tid; i < TT; i += 256) pml[i] = (char)pmb[i];

    // hoist Q fragments: 32 q-rows/wave = 2 row-frags x 2 k-halves
    bf16x8 qf[2][2];
#pragma unroll
    for (int qi = 0; qi < 2; ++qi)
#pragma unroll
        for (int hh = 0; hh < 2; ++hh)
            qf[qi][hh] = *(const bf16x8*)(Qh + (size_t)(qw + qi * 16 + lc) * HD + hh * 32 + lg * 8);

    f32x4 acc[2][4];
#pragma unroll
    for (int qi = 0; qi < 2; ++qi)
#pragma unroll
        for (int dc = 0; dc < 4; ++dc) acc[qi][dc] = (f32x4){0.f, 0.f, 0.f, 0.f};
    float mrow[2][4], lrow[2][4];
#pragma unroll
    for (int qi = 0; qi < 2; ++qi)
#pragma unroll
        for (int r = 0; r < 4; ++r) { mrow[qi][r] = -INFINITY; lrow[qi][r] = 0.f; }

    // staging lane constants: each wave stages 2x1KB slices of K and of V
    const int srow = lane >> 3;                     // row within 8-row slice
    const int sxor = ((lane & 7) * 16) ^ (srow << 4);  // pre-swizzled col byte

    __syncthreads();  // pml ready (full barrier OK: before the pipeline)

    const int nt = (qbase + QBLK) >> 6;
    int cur = 0;

#define STAGE(buf, kv0)                                                         \
    {                                                                           \
        _Pragma("unroll")                                                       \
        for (int j = 0; j < 2; ++j) {                                           \
            const int rr = (wid * 2 + j) * 8 + srow;                            \
            GLOAD16(Khb + (size_t)(kv0 + rr) * 128 + sxor,                      \
                    (char*)&Kl[buf][0] + (wid * 2 + j) * 1024);                 \
            GLOAD16(Vthb + (size_t)rr * (TT * 2) + (size_t)(kv0) * 2 + sxor,    \
                    (char*)&Vl[buf][0] + (wid * 2 + j) * 1024);                 \
        }                                                                       \
    }

    STAGE(0, 0);
    for (int t = 0; t < nt; ++t) {
        const int kv0 = t * KVB;
        if (t + 1 < nt) {
            STAGE(cur ^ 1, kv0 + KVB);
            WAITV4();  // current tile's 4 loads done; next tile's 4 in flight
        } else {
            WAITV0();
        }
        BAR();

        if (kv0 <= qw + 31) {
            const int ktmax = min(3, (qw + 31 - kv0) >> 4);
            f32x4 s[2][4];
#pragma unroll
            for (int kt = 0; kt < 4; ++kt) {
                s[0][kt] = (f32x4){0.f, 0.f, 0.f, 0.f};
                s[1][kt] = (f32x4){0.f, 0.f, 0.f, 0.f};
                if (kt <= ktmax) {
                    const int row = kt * 16 + lc;
                    const char* kb = (const char*)&Kl[cur][0] + row * 128;
                    const int x = (row & 7) << 4;
                    bf16x8 kf0 = *(const bf16x8*)(kb + ((lg * 16) ^ x));
                    bf16x8 kf1 = *(const bf16x8*)(kb + ((64 + lg * 16) ^ x));
#pragma unroll
                    for (int qi = 0; qi < 2; ++qi) {
                        s[qi][kt] = __builtin_amdgcn_mfma_f32_16x16x32_bf16(qf[qi][0], kf0,
                                                                            s[qi][kt], 0, 0, 0);
                        s[qi][kt] = __builtin_amdgcn_mfma_f32_16x16x32_bf16(qf[qi][1], kf1,
                                                                            s[qi][kt], 0, 0, 0);
                    }
                }
            }

#pragma unroll
            for (int qi = 0; qi < 2; ++qi)
#pragma unroll
                for (int r = 0; r < 4; ++r) {
                    const int qg = qw + qi * 16 + lg * 4 + r;
                    float v[4];
#pragma unroll
                    for (int kt = 0; kt < 4; ++kt) {
                        const int key = kv0 + kt * 16 + lc;
                        v[kt] = (key > qg || pml[key] == 0) ? -INFINITY : s[qi][kt][r];
                    }
                    float tmax = fmaxf(fmaxf(v[0], v[1]), fmaxf(v[2], v[3]));
                    tmax = fmaxf(tmax, __shfl_xor(tmax, 1));
                    tmax = fmaxf(tmax, __shfl_xor(tmax, 2));
                    tmax = fmaxf(tmax, __shfl_xor(tmax, 4));
                    tmax = fmaxf(tmax, __shfl_xor(tmax, 8));
                    const float mnew = fmaxf(mrow[qi][r], tmax);
                    const float esc = __builtin_amdgcn_exp2f(mrow[qi][r] - mnew);
                    float e[4];
                    float ps = 0.f;
#pragma unroll
                    for (int kt = 0; kt < 4; ++kt) {
                        e[kt] = __builtin_amdgcn_exp2f(v[kt] - mnew);
                        ps += e[kt];
                    }
                    ps += __shfl_xor(ps, 1);
                    ps += __shfl_xor(ps, 2);
                    ps += __shfl_xor(ps, 4);
                    ps += __shfl_xor(ps, 8);
                    lrow[qi][r] = lrow[qi][r] * esc + ps;
                    mrow[qi][r] = mnew;
#pragma unroll
                    for (int dc = 0; dc < 4; ++dc) acc[qi][dc][r] *= esc;
#pragma unroll
                    for (int kt = 0; kt < 4; ++kt)
                        Pl[wid][qi * 16 + lg * 4 + r][kt * 16 + lc] = f2bf(e[kt]);
                }

            // PV: A = P[32 q][64 k] (per-wave LDS), B = V^T tile (shared LDS)
            bf16x8 pa[2][2];
#pragma unroll
            for (int qi = 0; qi < 2; ++qi) {
                pa[qi][0] = *(const bf16x8*)(&Pl[wid][qi * 16 + lc][lg * 8]);
                pa[qi][1] = *(const bf16x8*)(&Pl[wid][qi * 16 + lc][32 + lg * 8]);
            }
#pragma unroll
            for (int dc = 0; dc < 4; ++dc) {
                const int row = dc * 16 + lc;
                const char* vb = (const char*)&Vl[cur][0] + row * 128;
                const int x = (row & 7) << 4;
                bf16x8 vb0 = *(const bf16x8*)(vb + ((lg * 16) ^ x));
                bf16x8 vb1 = *(const bf16x8*)(vb + ((64 + lg * 16) ^ x));
#pragma unroll
                for (int qi = 0; qi < 2; ++qi) {
                    acc[qi][dc] = __builtin_amdgcn_mfma_f32_16x16x32_bf16(pa[qi][0], vb0,
                                                                          acc[qi][dc], 0, 0, 0);
                    acc[qi][dc] = __builtin_amdgcn_mfma_f32_16x16x32_bf16(pa[qi][1], vb1,
                                                                          acc[qi][dc], 0, 0, 0);
                }
            }
        }
        BAR();
        cur ^= 1;
    }

    // epilogue: normalize, write [b*T+t][h*64+d] bf16
#pragma unroll
    for (int qi = 0; qi < 2; ++qi)
#pragma unroll
        for (int r = 0; r < 4; ++r) {
            float inv = 1.0f / lrow[qi][r];
            int qg = qw + qi * 16 + lg * 4 + r;
#pragma unroll
            for (int dc = 0; dc < 4; ++dc) {
                float val = acc[qi][dc][r] * inv;
                Og[((size_t)b * TT + qg) * DM + h * HD + dc * 16 + lc] = f2bf(val);
            }
        }
}

extern "C" void kernel_launch(void* const* d_in, const int* in_sizes, int n_in,
                              void* d_out, int out_size, void* d_ws, size_t ws_size,
                              hipStream_t stream) {
    const float* xq = (const float*)d_in[0];
    const float* xk = (const float*)d_in[1];
    const float* xv = (const float*)d_in[2];
    const int* pmask = (const int*)d_in[3];
    const float* Wq = (const float*)d_in[4];
    const float* bq = (const float*)d_in[5];
    const float* Wk = (const float*)d_in[6];
    const float* bk = (const float*)d_in[7];
    const float* Wv = (const float*)d_in[8];
    const float* bv = (const float*)d_in[9];
    const float* Wo = (const float*)d_in[10];
    const float* bo = (const float*)d_in[11];

    char* ws = (char*)d_ws;
    const size_t WT = (size_t)DM * DM * 2;             // 2 MB per transposed weight
    const size_t QKV = (size_t)NB * NH * TT * HD * 2;  // 16 MB each
    unsigned short* WqT = (unsigned short*)(ws + 0 * WT);
    unsigned short* WkT = (unsigned short*)(ws + 1 * WT);
    unsigned short* WvT = (unsigned short*)(ws + 2 * WT);
    unsigned short* WoT = (unsigned short*)(ws + 3 * WT);
    unsigned short* Qb = (unsigned short*)(ws + 4 * WT);
    unsigned short* Kb = (unsigned short*)(ws + 4 * WT + QKV);
    unsigned short* Vb = (unsigned short*)(ws + 4 * WT + 2 * QKV);
    unsigned short* Vt = (unsigned short*)(ws + 4 * WT + 3 * QKV);
    unsigned short* Ob = Vb;  // Vb dead after k_transpose_v; reuse for attn out

    dim3 tb(32, 8);
    k_transpose_w<<<dim3(32, 32), tb, 0, stream>>>(Wq, WqT);
    k_transpose_w<<<dim3(32, 32), tb, 0, stream>>>(Wk, WkT);
    k_transpose_w<<<dim3(32, 32), tb, 0, stream>>>(Wv, WvT);
    k_transpose_w<<<dim3(32, 32), tb, 0, stream>>>(Wo, WoT);

    const float qscale = 0.125f * 1.44269504088896340736f;  // 1/sqrt(64) * log2(e)
    dim3 gg(64, 8);  // M/128, N/128
    k_gemm<0, false><<<gg, 256, 0, stream>>>(xq, WqT, bq, Qb, qscale);
    k_gemm<0, false><<<gg, 256, 0, stream>>>(xk, WkT, bk, Kb, 1.0f);
    k_gemm<0, false><<<gg, 256, 0, stream>>>(xv, WvT, bv, Vb, 1.0f);

    k_transpose_v<<<dim3(TT / 32, HD / 32, NB * NH), tb, 0, stream>>>(Vb, Vt);

    k_attn<<<dim3(TT / QBLK, NB * NH), 256, 0, stream>>>(Qb, Kb, Vt, pmask, Ob);

    k_gemm<1, true><<<gg, 256, 0, stream>>>(Ob, WoT, bo, d_out, 1.0f);
}

// Round 6
// 280.642 us; speedup vs baseline: 2.2092x; 1.7995x over previous
//
#include <hip/hip_runtime.h>
#include <hip/hip_bf16.h>
#include <cstdint>

#define NB 4
#define TT 2048
#define DM 1024
#define NH 16
#define HD 64
#define QBLK 256
#define KVB 64

typedef __attribute__((ext_vector_type(8))) short bf16x8;
typedef __attribute__((ext_vector_type(4))) float f32x4;
typedef __attribute__((ext_vector_type(16))) float f32x16;
typedef __attribute__((ext_vector_type(4))) float float4v;
typedef __attribute__((ext_vector_type(4))) int i32x4;

static __device__ __forceinline__ unsigned short f2bf(float x) {
    unsigned int u = __float_as_uint(x);
    unsigned int r = (u + 0x7fffu + ((u >> 16) & 1u)) >> 16;
    return (unsigned short)r;
}
static __device__ __forceinline__ uint32_t pk2bf(float lo, float hi) {
    return (uint32_t)f2bf(lo) | ((uint32_t)f2bf(hi) << 16);
}

#define GLOAD16(gp, lp) __builtin_amdgcn_global_load_lds(                 \
    (const __attribute__((address_space(1))) void*)(gp),                  \
    (__attribute__((address_space(3))) void*)(lp), 16, 0, 0)
#define BAR() asm volatile("s_barrier" ::: "memory")
#define WAITV2() asm volatile("s_waitcnt vmcnt(2)" ::: "memory")
#define WAITV0() asm volatile("s_waitcnt vmcnt(0)" ::: "memory")

// ---- W[k][n] f32 -> Wt[n][k] bf16 (transpose + convert) ----
__global__ __launch_bounds__(256) void k_transpose_w(const float* __restrict__ W,
                                                     unsigned short* __restrict__ Wt) {
    __shared__ unsigned short tile[32][33];
    int tx = threadIdx.x, ty = threadIdx.y;
    int kb = blockIdx.x * 32, nb = blockIdx.y * 32;
#pragma unroll
    for (int i = 0; i < 4; ++i)
        tile[ty + i * 8][tx] = f2bf(W[(size_t)(kb + ty + i * 8) * DM + nb + tx]);
    __syncthreads();
#pragma unroll
    for (int i = 0; i < 4; ++i)
        Wt[(size_t)(nb + ty + i * 8) * DM + kb + tx] = tile[tx][ty + i * 8];
}

// ---- V[bh][t][d] bf16 -> Vt[bh][d][t] bf16 ----
__global__ __launch_bounds__(256) void k_transpose_v(const unsigned short* __restrict__ V,
                                                     unsigned short* __restrict__ Vt) {
    __shared__ unsigned short tile[32][34];
    int tx = threadIdx.x, ty = threadIdx.y;
    int bh = blockIdx.z;
    int t0 = blockIdx.x * 32, d0 = blockIdx.y * 32;
    const unsigned short* src = V + (size_t)bh * TT * HD;
    unsigned short* dst = Vt + (size_t)bh * HD * TT;
#pragma unroll
    for (int i = 0; i < 4; ++i)
        tile[ty + i * 8][tx] = src[(size_t)(t0 + ty + i * 8) * HD + d0 + tx];
    __syncthreads();
#pragma unroll
    for (int i = 0; i < 4; ++i)
        dst[(size_t)(d0 + ty + i * 8) * TT + t0 + tx] = tile[tx][ty + i * 8];
}

// ---- GEMM: C[M=8192][1024] = A[M][1024] @ W[1024][1024] (+bias)*scale ----
template <int OUT_MODE, bool A_BF16>
__global__ __launch_bounds__(256) void k_gemm(const void* __restrict__ Av,
                                              const unsigned short* __restrict__ Bt,
                                              const float* __restrict__ bias,
                                              void* __restrict__ Cv, float scale) {
    __shared__ __align__(16) unsigned short As[128][56];
    __shared__ __align__(16) unsigned short Bs[128][56];
    const int tid = threadIdx.x;
    const int lane = tid & 63, wid = tid >> 6;
    const int lg = lane >> 4, lc = lane & 15;
    const int wm = wid >> 1, wn = wid & 1;
    const int m0 = blockIdx.x * 128, n0 = blockIdx.y * 128;

    f32x4 acc[4][4];
#pragma unroll
    for (int mi = 0; mi < 4; ++mi)
#pragma unroll
        for (int ni = 0; ni < 4; ++ni)
            acc[mi][ni] = (f32x4){0.f, 0.f, 0.f, 0.f};

    for (int k0 = 0; k0 < DM; k0 += 32) {
        __syncthreads();
        if (!A_BF16) {
            const float* A = (const float*)Av;
#pragma unroll
            for (int p = 0; p < 4; ++p) {
                int r = p * 32 + (tid >> 3);
                int cs = (tid & 7) * 4;
                float4v v = *(const float4v*)(A + (size_t)(m0 + r) * DM + k0 + cs);
                As[r][cs + 0] = f2bf(v[0]);
                As[r][cs + 1] = f2bf(v[1]);
                As[r][cs + 2] = f2bf(v[2]);
                As[r][cs + 3] = f2bf(v[3]);
            }
        } else {
            const unsigned short* A = (const unsigned short*)Av;
#pragma unroll
            for (int p = 0; p < 2; ++p) {
                int r = p * 64 + (tid >> 2), seg = tid & 3;
                bf16x8 v = *(const bf16x8*)(A + (size_t)(m0 + r) * DM + k0 + seg * 8);
                *(bf16x8*)(&As[r][seg * 8]) = v;
            }
        }
#pragma unroll
        for (int p = 0; p < 2; ++p) {
            int r = p * 64 + (tid >> 2), seg = tid & 3;
            bf16x8 v = *(const bf16x8*)(Bt + (size_t)(n0 + r) * DM + k0 + seg * 8);
            *(bf16x8*)(&Bs[r][seg * 8]) = v;
        }
        __syncthreads();

        bf16x8 af[4], bfr[4];
#pragma unroll
        for (int mi = 0; mi < 4; ++mi)
            af[mi] = *(const bf16x8*)(&As[wm * 64 + mi * 16 + lc][lg * 8]);
#pragma unroll
        for (int ni = 0; ni < 4; ++ni)
            bfr[ni] = *(const bf16x8*)(&Bs[wn * 64 + ni * 16 + lc][lg * 8]);
#pragma unroll
        for (int mi = 0; mi < 4; ++mi)
#pragma unroll
            for (int ni = 0; ni < 4; ++ni)
                acc[mi][ni] = __builtin_amdgcn_mfma_f32_16x16x32_bf16(af[mi], bfr[ni],
                                                                      acc[mi][ni], 0, 0, 0);
    }

#pragma unroll
    for (int mi = 0; mi < 4; ++mi)
#pragma unroll
        for (int ni = 0; ni < 4; ++ni)
#pragma unroll
            for (int r = 0; r < 4; ++r) {
                int m = m0 + wm * 64 + mi * 16 + lg * 4 + r;
                int n = n0 + wn * 64 + ni * 16 + lc;
                float val = (acc[mi][ni][r] + bias[n]) * scale;
                if (OUT_MODE == 0) {
                    int b = m >> 11, t = m & (TT - 1), h = n >> 6, d = n & 63;
                    ((unsigned short*)Cv)[(((size_t)b * NH + h) * TT + t) * HD + d] = f2bf(val);
                } else {
                    ((float*)Cv)[(size_t)m * DM + n] = val;
                }
            }
}

// ---- flash attention, swapped-QK^T 32x32 MFMA, in-register softmax ----
// Q,K bf16 [bh][t][64]; Vt bf16 [bh][d][t]; out bf16 [b*T+t][h*64+d]
// Q pre-scaled by log2(e)/sqrt(D). 8 waves x 32 q-rows. KV tiles of 64,
// double-buffered LDS (K [key][d], V^T [d][key], XOR-swizzled byte^=(row&7)<<4,
// staged via global_load_lds with pre-swizzled source).
// S^T = mfma(K, Q): col=lane&31=q, reg r holds key (r&3)+8*(r>>2)+4*(lane>>5).
// NOTE: each double-buffer half is 8192 B — read offset MUST be cur*8192
// (cur*16384 was rounds 4/5's NaN: buf-1 V reads hit unallocated LDS).
__global__ __launch_bounds__(512) void k_attn(const unsigned short* __restrict__ Qg,
                                              const unsigned short* __restrict__ Kg,
                                              const unsigned short* __restrict__ Vtg,
                                              const int* __restrict__ pm,
                                              unsigned short* __restrict__ Og) {
    __shared__ __align__(16) unsigned short Kl[2][KVB * HD];  // 8 KB per buf
    __shared__ __align__(16) unsigned short Vl[2][KVB * HD];  // V^T tile [d][key]
    __shared__ uint64_t pmbits[TT / 64];

    const int bh = blockIdx.y;
    const int b = bh >> 4, h = bh & 15;
    const int qb = gridDim.x - 1 - blockIdx.x;  // heavy blocks first
    const int qbase = qb * QBLK;
    const int tid = threadIdx.x;
    const int wid = tid >> 6, lane = tid & 63;
    const int hi = lane >> 5, l31 = lane & 31;
    const int q0 = qbase + wid * 32;
    const int q = q0 + l31;

    const unsigned short* Qh = Qg + (size_t)bh * TT * HD;
    const char* Khb = (const char*)(Kg + (size_t)bh * TT * HD);
    const char* Vthb = (const char*)(Vtg + (size_t)bh * HD * TT);
    const int* pmb = pm + b * TT;

    // staging constants: 1 GLOAD16/thread for K, 1 for V per tile
    const int srow = lane >> 3;                         // 0..7
    const int scolx = ((lane & 7) * 16) ^ (srow << 4);  // pre-swizzled col byte
    char* const kdst = (char*)&Kl[0][0];                // + buf*8192 + wid*1024
    char* const vdst = (char*)&Vl[0][0];

    // prologue: stage tile 0 (drained by the __syncthreads below)
    GLOAD16(Khb + (size_t)(wid * 8 + srow) * 128 + scolx, kdst + wid * 1024);
    GLOAD16(Vthb + (size_t)(wid * 8 + srow) * 4096 + scolx, vdst + wid * 1024);

    // padding-mask bitmasks (one u64 per 64-key tile); bit=1 -> key valid
#pragma unroll
    for (int it = 0; it < 4; ++it) {
        const int g = wid + it * 8;
        unsigned long long msk = __ballot(pmb[g * 64 + lane] != 0);
        if (lane == 0) pmbits[g] = msk;
    }

    // hoist Q fragments (B-operand: col q = lane&31, d-chunk dd*16 + hi*8)
    bf16x8 qf[4];
#pragma unroll
    for (int dd = 0; dd < 4; ++dd)
        qf[dd] = *(const bf16x8*)((const char*)Qh + (size_t)q * 128 + dd * 32 + hi * 16);

    f32x16 o0, o1;
#pragma unroll
    for (int r = 0; r < 16; ++r) { o0[r] = 0.f; o1[r] = 0.f; }
    float mrow = -INFINITY, lrow = 0.f;

    __syncthreads();  // pmbits visible; tile-0 loads drained (vmcnt 0)

    const int nt = (qbase + QBLK) >> 6;
    int cur = 0;
    for (int t = 0; t < nt; ++t) {
        const int kv0 = t << 6;
        if (t + 1 < nt) {
            const int kn = kv0 + KVB;
            const int nb = (cur ^ 1) * 8192 + wid * 1024;
            GLOAD16(Khb + (size_t)(kn + wid * 8 + srow) * 128 + scolx, kdst + nb);
            GLOAD16(Vthb + (size_t)(wid * 8 + srow) * 4096 + (size_t)kn * 2 + scolx, vdst + nb);
            WAITV2();  // current tile's 2 loads done; next tile's 2 in flight
        } else {
            WAITV0();
        }
        BAR();

        if (kv0 <= q0 + 31) {  // wave-uniform causal skip
            const uint64_t vb = pmbits[kv0 >> 6];
            const uint32_t pm0 = ((uint32_t)vb) >> (4 * hi);
            const uint32_t pm1 = ((uint32_t)(vb >> 32)) >> (4 * hi);
            const bool allvalid = (vb == ~0ull);
            const bool do2 = (kv0 + 32 <= q0 + 31);
            const bool needmask = (kv0 + 63 > q0) || !allvalid;
            const char* kb = (const char*)&Kl[0][0] + cur * 8192;   // FIX: was 16384
            const char* vbp = (const char*)&Vl[0][0] + cur * 8192;  // FIX: was 16384

            // ---- QK^T: S^T[key][q] ----
            f32x16 st0, st1;
#pragma unroll
            for (int r = 0; r < 16; ++r) { st0[r] = 0.f; st1[r] = 0.f; }
            __builtin_amdgcn_s_setprio(1);
#pragma unroll
            for (int dd = 0; dd < 4; ++dd) {
                const int row = l31;
                bf16x8 kf = *(const bf16x8*)(kb + row * 128 + ((dd * 32 + hi * 16) ^ ((row & 7) << 4)));
                st0 = __builtin_amdgcn_mfma_f32_32x32x16_bf16(kf, qf[dd], st0, 0, 0, 0);
            }
            if (do2) {
#pragma unroll
                for (int dd = 0; dd < 4; ++dd) {
                    const int row = 32 + l31;
                    bf16x8 kf = *(const bf16x8*)(kb + row * 128 + ((dd * 32 + hi * 16) ^ ((row & 7) << 4)));
                    st1 = __builtin_amdgcn_mfma_f32_32x32x16_bf16(kf, qf[dd], st1, 0, 0, 0);
                }
            }
            __builtin_amdgcn_s_setprio(0);

            // ---- masking (causal + padding), lane-local ----
            const int qr = q - kv0 - 4 * hi;
            if (needmask) {
#pragma unroll
                for (int r = 0; r < 16; ++r) {
                    const int c = (r & 3) + 8 * (r >> 2);
                    st0[r] = (((pm0 >> c) & 1) && (c <= qr)) ? st0[r] : -INFINITY;
                }
                if (do2) {
#pragma unroll
                    for (int r = 0; r < 16; ++r) {
                        const int c = (r & 3) + 8 * (r >> 2);
                        st1[r] = (((pm1 >> c) & 1) && (c + 32 <= qr)) ? st1[r] : -INFINITY;
                    }
                }
            }

            // ---- online softmax, fully in-register, NaN-proof ----
            float mloc = -INFINITY;
#pragma unroll
            for (int r = 0; r < 16; ++r) mloc = fmaxf(mloc, st0[r]);
            if (do2) {
#pragma unroll
                for (int r = 0; r < 16; ++r) mloc = fmaxf(mloc, st1[r]);
            }
            const float cmax = fmaxf(mloc, __shfl_xor(mloc, 32, 64));
            const float mnew = fmaxf(mrow, cmax);
            const float msafe = fmaxf(mnew, -1.0e30f);  // finite stand-in
            const float esc = __builtin_amdgcn_exp2f(fmaxf(mrow - msafe, -200.0f));
#pragma unroll
            for (int r = 0; r < 16; ++r) { o0[r] *= esc; o1[r] *= esc; }
            lrow *= esc;
            mrow = mnew;

            // exponentials (clamped: masked/-inf entries -> 0, no NaN possible)
            float tot = 0.f;
#pragma unroll
            for (int r = 0; r < 16; ++r) {
                st0[r] = __builtin_amdgcn_exp2f(fmaxf(st0[r] - msafe, -200.0f));
                tot += st0[r];
            }
            if (do2) {
#pragma unroll
                for (int r = 0; r < 16; ++r) {
                    st1[r] = __builtin_amdgcn_exp2f(fmaxf(st1[r] - msafe, -200.0f));
                    tot += st1[r];
                }
            }
            lrow += tot + __shfl_xor(tot, 32, 64);

            // ---- P -> bf16 B-fragments (pair redistribution via shfl) + PV ----
            // own packs (this lane's hi_l): A0={16kc+4hi_l+0,1} A1={+2,3}
            //                               C0={16kc+4hi_l+8,9} C1={+10,11}
            // slot s needs keys 16kc + 8*hi + {2s,2s+1}:
            //   slot0 = hi ? partnerC0 : A0;  slot1 = hi ? partnerC1 : A1
            //   slot2 = hi ? C0 : partnerA0;  slot3 = hi ? C1 : partnerA1
            __builtin_amdgcn_s_setprio(1);
#pragma unroll
            for (int kc = 0; kc < 2; ++kc) {
                uint32_t A0 = pk2bf(st0[kc * 8 + 0], st0[kc * 8 + 1]);
                uint32_t A1 = pk2bf(st0[kc * 8 + 2], st0[kc * 8 + 3]);
                uint32_t C0 = pk2bf(st0[kc * 8 + 4], st0[kc * 8 + 5]);
                uint32_t C1 = pk2bf(st0[kc * 8 + 6], st0[kc * 8 + 7]);
                uint32_t oA0 = __shfl_xor(A0, 32, 64), oA1 = __shfl_xor(A1, 32, 64);
                uint32_t oC0 = __shfl_xor(C0, 32, 64), oC1 = __shfl_xor(C1, 32, 64);
                i32x4 pf = {(int)(hi ? oC0 : A0), (int)(hi ? oC1 : A1),
                            (int)(hi ? C0 : oA0), (int)(hi ? C1 : oA1)};
                bf16x8 pb = *(bf16x8*)&pf;
                const int colb = kc * 32 + hi * 16;
                {
                    const int row = l31;
                    bf16x8 vf = *(const bf16x8*)(vbp + row * 128 + (colb ^ ((row & 7) << 4)));
                    o0 = __builtin_amdgcn_mfma_f32_32x32x16_bf16(vf, pb, o0, 0, 0, 0);
                }
                {
                    const int row = 32 + l31;
                    bf16x8 vf = *(const bf16x8*)(vbp + row * 128 + (colb ^ ((row & 7) << 4)));
                    o1 = __builtin_amdgcn_mfma_f32_32x32x16_bf16(vf, pb, o1, 0, 0, 0);
                }
            }
            if (do2) {
#pragma unroll
                for (int kc = 0; kc < 2; ++kc) {
                    uint32_t A0 = pk2bf(st1[kc * 8 + 0], st1[kc * 8 + 1]);
                    uint32_t A1 = pk2bf(st1[kc * 8 + 2], st1[kc * 8 + 3]);
                    uint32_t C0 = pk2bf(st1[kc * 8 + 4], st1[kc * 8 + 5]);
                    uint32_t C1 = pk2bf(st1[kc * 8 + 6], st1[kc * 8 + 7]);
                    uint32_t oA0 = __shfl_xor(A0, 32, 64), oA1 = __shfl_xor(A1, 32, 64);
                    uint32_t oC0 = __shfl_xor(C0, 32, 64), oC1 = __shfl_xor(C1, 32, 64);
                    i32x4 pf = {(int)(hi ? oC0 : A0), (int)(hi ? oC1 : A1),
                                (int)(hi ? C0 : oA0), (int)(hi ? C1 : oA1)};
                    bf16x8 pb = *(bf16x8*)&pf;
                    const int colb = (2 + kc) * 32 + hi * 16;
                    {
                        const int row = l31;
                        bf16x8 vf = *(const bf16x8*)(vbp + row * 128 + (colb ^ ((row & 7) << 4)));
                        o0 = __builtin_amdgcn_mfma_f32_32x32x16_bf16(vf, pb, o0, 0, 0, 0);
                    }
                    {
                        const int row = 32 + l31;
                        bf16x8 vf = *(const bf16x8*)(vbp + row * 128 + (colb ^ ((row & 7) << 4)));
                        o1 = __builtin_amdgcn_mfma_f32_32x32x16_bf16(vf, pb, o1, 0, 0, 0);
                    }
                }
            }
            __builtin_amdgcn_s_setprio(0);
        }
        BAR();
        cur ^= 1;
    }

    // ---- epilogue: normalize, write bf16 [b*T+q][h*64+d], 8B packed stores ----
    // o0[r] = O[q][d=(r&3)+8*(r>>2)+4*hi], o1: d+32
    const float inv = (lrow > 0.f) ? (1.0f / lrow) : 0.f;
    unsigned short* orow = Og + ((size_t)(b * TT + q)) * DM + h * HD;
#pragma unroll
    for (int g4 = 0; g4 < 4; ++g4) {
        uint32_t w0 = pk2bf(o0[g4 * 4 + 0] * inv, o0[g4 * 4 + 1] * inv);
        uint32_t w1 = pk2bf(o0[g4 * 4 + 2] * inv, o0[g4 * 4 + 3] * inv);
        *(uint2*)(orow + g4 * 8 + 4 * hi) = make_uint2(w0, w1);
    }
#pragma unroll
    for (int g4 = 0; g4 < 4; ++g4) {
        uint32_t w0 = pk2bf(o1[g4 * 4 + 0] * inv, o1[g4 * 4 + 1] * inv);
        uint32_t w1 = pk2bf(o1[g4 * 4 + 2] * inv, o1[g4 * 4 + 3] * inv);
        *(uint2*)(orow + 32 + g4 * 8 + 4 * hi) = make_uint2(w0, w1);
    }
}

extern "C" void kernel_launch(void* const* d_in, const int* in_sizes, int n_in,
                              void* d_out, int out_size, void* d_ws, size_t ws_size,
                              hipStream_t stream) {
    const float* xq = (const float*)d_in[0];
    const float* xk = (const float*)d_in[1];
    const float* xv = (const float*)d_in[2];
    const int* pmask = (const int*)d_in[3];
    const float* Wq = (const float*)d_in[4];
    const float* bq = (const float*)d_in[5];
    const float* Wk = (const float*)d_in[6];
    const float* bk = (const float*)d_in[7];
    const float* Wv = (const float*)d_in[8];
    const float* bv = (const float*)d_in[9];
    const float* Wo = (const float*)d_in[10];
    const float* bo = (const float*)d_in[11];

    char* ws = (char*)d_ws;
    const size_t WT = (size_t)DM * DM * 2;             // 2 MB per transposed weight
    const size_t QKV = (size_t)NB * NH * TT * HD * 2;  // 16 MB each
    unsigned short* WqT = (unsigned short*)(ws + 0 * WT);
    unsigned short* WkT = (unsigned short*)(ws + 1 * WT);
    unsigned short* WvT = (unsigned short*)(ws + 2 * WT);
    unsigned short* WoT = (unsigned short*)(ws + 3 * WT);
    unsigned short* Qb = (unsigned short*)(ws + 4 * WT);
    unsigned short* Kb = (unsigned short*)(ws + 4 * WT + QKV);
    unsigned short* Vb = (unsigned short*)(ws + 4 * WT + 2 * QKV);
    unsigned short* Vt = (unsigned short*)(ws + 4 * WT + 3 * QKV);
    unsigned short* Ob = Vb;  // Vb dead after k_transpose_v; reuse for attn out

    dim3 tb(32, 8);
    k_transpose_w<<<dim3(32, 32), tb, 0, stream>>>(Wq, WqT);
    k_transpose_w<<<dim3(32, 32), tb, 0, stream>>>(Wk, WkT);
    k_transpose_w<<<dim3(32, 32), tb, 0, stream>>>(Wv, WvT);
    k_transpose_w<<<dim3(32, 32), tb, 0, stream>>>(Wo, WoT);

    const float qscale = 0.125f * 1.44269504088896340736f;  // 1/sqrt(64) * log2(e)
    dim3 gg(64, 8);  // M/128, N/128
    k_gemm<0, false><<<gg, 256, 0, stream>>>(xq, WqT, bq, Qb, qscale);
    k_gemm<0, false><<<gg, 256, 0, stream>>>(xk, WkT, bk, Kb, 1.0f);
    k_gemm<0, false><<<gg, 256, 0, stream>>>(xv, WvT, bv, Vb, 1.0f);

    k_transpose_v<<<dim3(TT / 32, HD / 32, NB * NH), tb, 0, stream>>>(Vb, Vt);

    k_attn<<<dim3(TT / QBLK, NB * NH), 512, 0, stream>>>(Qb, Kb, Vt, pmask, Ob);

    k_gemm<1, true><<<gg, 256, 0, stream>>>(Ob, WoT, bo, d_out, 1.0f);
}